// Round 1
// baseline (2572.996 us; speedup 1.0000x reference)
//
#include <hip/hip_runtime.h>
#include <hip/hip_bf16.h>
#include <cstdint>
#include <cstddef>

// ---------------------------------------------------------------------------
// Host-side reproduction of np.random.RandomState(2).permutation(64):
// MT19937 seeded with init_genrand(2) (numpy mt19937_seed), Fisher-Yates
// using numpy's random_interval (mask + rejection, 32-bit draws for max<2^32).
// Mask bit d = (perm[d] >= 38)  [num_masked = int((1-ln(1.5))*64) = 38].
// ---------------------------------------------------------------------------
static uint64_t compute_mask_bits() {
    uint32_t mt[624];
    mt[0] = 2u;
    for (int i = 1; i < 624; i++)
        mt[i] = 1812433253u * (mt[i - 1] ^ (mt[i - 1] >> 30)) + (uint32_t)i;
    int mti = 624;
    auto genrand = [&]() -> uint32_t {
        if (mti >= 624) {
            for (int k = 0; k < 624; k++) {
                uint32_t y = (mt[k] & 0x80000000u) | (mt[(k + 1) % 624] & 0x7fffffffu);
                mt[k] = mt[(k + 397) % 624] ^ (y >> 1) ^ ((y & 1u) ? 2567483615u : 0u);
            }
            mti = 0;
        }
        uint32_t y = mt[mti++];
        y ^= y >> 11;
        y ^= (y << 7) & 2636928640u;
        y ^= (y << 15) & 4022730752u;
        y ^= y >> 18;
        return y;
    };
    int arr[64];
    for (int i = 0; i < 64; i++) arr[i] = i;
    for (int i = 63; i >= 1; i--) {
        uint32_t mask = (uint32_t)i;
        mask |= mask >> 1; mask |= mask >> 2; mask |= mask >> 4;
        mask |= mask >> 8; mask |= mask >> 16;
        uint32_t v;
        do { v = genrand() & mask; } while (v > (uint32_t)i);
        int tmp = arr[i]; arr[i] = arr[v]; arr[v] = tmp;
    }
    uint64_t bits = 0;
    for (int d = 0; d < 64; d++)
        if (arr[d] >= 38) bits |= (1ull << d);
    return bits;
}

// ---------------------------------------------------------------------------
// CSR build kernels
// ---------------------------------------------------------------------------
__global__ void hist_kernel(const int* __restrict__ rows, int* __restrict__ cnt, int e) {
    int i = blockIdx.x * 256 + threadIdx.x;
    if (i < e) atomicAdd(&cnt[rows[i]], 1);
}

__global__ void scan1_kernel(const int* __restrict__ cnt, int* __restrict__ rp,
                             int* __restrict__ bsums, int n) {
    __shared__ int sh[256];
    int t = threadIdx.x;
    int base = blockIdx.x * 1024 + t * 4;
    int v0 = 0, v1 = 0, v2 = 0, v3 = 0;
    if (base + 3 < n) {
        int4 q = *(const int4*)(cnt + base);
        v0 = q.x; v1 = q.y; v2 = q.z; v3 = q.w;
    } else {
        if (base + 0 < n) v0 = cnt[base + 0];
        if (base + 1 < n) v1 = cnt[base + 1];
        if (base + 2 < n) v2 = cnt[base + 2];
        if (base + 3 < n) v3 = cnt[base + 3];
    }
    int total = v0 + v1 + v2 + v3;
    sh[t] = total;
    __syncthreads();
    for (int off = 1; off < 256; off <<= 1) {
        int x = (t >= off) ? sh[t - off] : 0;
        __syncthreads();
        sh[t] += x;
        __syncthreads();
    }
    int excl = sh[t] - total;
    if (base + 0 < n) rp[base + 0] = excl;
    if (base + 1 < n) rp[base + 1] = excl + v0;
    if (base + 2 < n) rp[base + 2] = excl + v0 + v1;
    if (base + 3 < n) rp[base + 3] = excl + v0 + v1 + v2;
    if (t == 255) bsums[blockIdx.x] = sh[255];
}

__global__ void scan2_kernel(int* __restrict__ bsums, int nb) {
    __shared__ int sh[256];
    int t = threadIdx.x;
    int v = (t < nb) ? bsums[t] : 0;
    sh[t] = v;
    __syncthreads();
    for (int off = 1; off < 256; off <<= 1) {
        int x = (t >= off) ? sh[t - off] : 0;
        __syncthreads();
        sh[t] += x;
        __syncthreads();
    }
    if (t < nb) bsums[t] = sh[t] - v;  // exclusive
}

__global__ void scan3_kernel(int* __restrict__ rp, const int* __restrict__ bsums,
                             int n, int e_total) {
    int i = blockIdx.x * 256 + threadIdx.x;
    if (i < n) rp[i] += bsums[i >> 10];
    if (i == 0) rp[n] = e_total;
}

__global__ void scatter_kernel(const int* __restrict__ rows, const int* __restrict__ cols,
                               const float* __restrict__ vals, const int* __restrict__ rp,
                               int* __restrict__ cur, int* __restrict__ ccol,
                               float* __restrict__ cval, int e) {
    int i = blockIdx.x * 256 + threadIdx.x;
    if (i >= e) return;
    int rsrc = rows[i];
    int pos = rp[rsrc] + atomicAdd(&cur[rsrc], 1);
    ccol[pos] = cols[i];
    cval[pos] = vals[i];
}

// ---------------------------------------------------------------------------
// Per-rating MLP: h = leaky_relu(x @ W1a + c1) @ W2 + b2
// block = 256 threads, 64 rows/block, 4x4 register blocking, D = 64.
// Also does prev = h and out_acc += h.
// ---------------------------------------------------------------------------
__global__ __launch_bounds__(256) void mlp_kernel(
    const float* __restrict__ user_emb, const float* __restrict__ item_emb,
    const float* __restrict__ rating_emb, const float* __restrict__ W1,
    const float* __restrict__ b1, const float* __restrict__ W2,
    const float* __restrict__ b2, float* __restrict__ prev,
    float* __restrict__ out_acc, int r, int n_rows, int U) {
    __shared__ float sW1[64 * 64];  // [k][j]
    __shared__ float sW2[64 * 64];  // [k][j]
    __shared__ float sXT[64 * 64];  // [k][i] transposed input tile
    __shared__ float sTT[64 * 64];  // [k][i] transposed tmp
    __shared__ float sc1[64];
    __shared__ float sb2v[64];

    int t = threadIdx.x;
    int row0 = blockIdx.x * 64;
    const float* W1r = W1 + (size_t)r * (128 * 64);
    const float* W2r = W2 + (size_t)r * (64 * 64);

    #pragma unroll
    for (int q = 0; q < 4; q++) {
        int f = t + 256 * q;
        int k = f >> 4, c = (f & 15) * 4;
        *(float4*)(sW1 + k * 64 + c) = *(const float4*)(W1r + k * 64 + c);
        *(float4*)(sW2 + k * 64 + c) = *(const float4*)(W2r + k * 64 + c);
    }
    #pragma unroll
    for (int q = 0; q < 4; q++) {
        int f = t + 256 * q;
        int i = f >> 4, c = (f & 15) * 4;
        int nrow = row0 + i;
        float4 xv = make_float4(0.f, 0.f, 0.f, 0.f);
        if (nrow < n_rows) {
            const float* src = (nrow < U) ? (user_emb + (size_t)nrow * 64)
                                          : (item_emb + (size_t)(nrow - U) * 64);
            xv = *(const float4*)(src + c);
        }
        sXT[(c + 0) * 64 + i] = xv.x;
        sXT[(c + 1) * 64 + i] = xv.y;
        sXT[(c + 2) * 64 + i] = xv.z;
        sXT[(c + 3) * 64 + i] = xv.w;
    }
    if (t < 64) {
        float acc = b1[r * 64 + t];
        for (int k = 0; k < 64; k++)
            acc += rating_emb[r * 64 + k] * W1r[(64 + k) * 64 + t];
        sc1[t] = acc;
    } else if (t < 128) {
        sb2v[t - 64] = b2[r * 64 + (t - 64)];
    }
    __syncthreads();

    int i0 = (t & 15) * 4, j0 = (t >> 4) * 4;
    float acc[4][4];
    #pragma unroll
    for (int a = 0; a < 4; a++)
        #pragma unroll
        for (int b = 0; b < 4; b++) acc[a][b] = sc1[j0 + b];
    for (int k = 0; k < 64; k++) {
        float4 xv = *(const float4*)(sXT + k * 64 + i0);
        float4 wv = *(const float4*)(sW1 + k * 64 + j0);
        float xs[4] = {xv.x, xv.y, xv.z, xv.w};
        float ws[4] = {wv.x, wv.y, wv.z, wv.w};
        #pragma unroll
        for (int a = 0; a < 4; a++)
            #pragma unroll
            for (int b = 0; b < 4; b++) acc[a][b] += xs[a] * ws[b];
    }
    #pragma unroll
    for (int a = 0; a < 4; a++)
        #pragma unroll
        for (int b = 0; b < 4; b++) {
            float v = acc[a][b];
            v = (v >= 0.f) ? v : 0.01f * v;  // leaky_relu, slope 0.01
            sTT[(j0 + b) * 64 + (i0 + a)] = v;
        }
    __syncthreads();

    #pragma unroll
    for (int a = 0; a < 4; a++)
        #pragma unroll
        for (int b = 0; b < 4; b++) acc[a][b] = sb2v[j0 + b];
    for (int k = 0; k < 64; k++) {
        float4 xv = *(const float4*)(sTT + k * 64 + i0);
        float4 wv = *(const float4*)(sW2 + k * 64 + j0);
        float xs[4] = {xv.x, xv.y, xv.z, xv.w};
        float ws[4] = {wv.x, wv.y, wv.z, wv.w};
        #pragma unroll
        for (int a = 0; a < 4; a++)
            #pragma unroll
            for (int b = 0; b < 4; b++) acc[a][b] += xs[a] * ws[b];
    }
    #pragma unroll
    for (int a = 0; a < 4; a++) {
        int nrow = row0 + i0 + a;
        if (nrow < n_rows) {
            float4 hv = make_float4(acc[a][0], acc[a][1], acc[a][2], acc[a][3]);
            *(float4*)(prev + (size_t)nrow * 64 + j0) = hv;
            float4 ov = *(const float4*)(out_acc + (size_t)nrow * 64 + j0);
            ov.x += hv.x; ov.y += hv.y; ov.z += hv.z; ov.w += hv.w;
            *(float4*)(out_acc + (size_t)nrow * 64 + j0) = ov;
        }
    }
}

// ---------------------------------------------------------------------------
// Gather-SpMM: one wave (64 lanes = 64 dims) per output row.
// next[n][d] = sum_{e in row n} val_e * prev[col_e][d]; layer-2 mask combine;
// out_acc += result. No atomics.
// ---------------------------------------------------------------------------
__global__ __launch_bounds__(256) void spmm_kernel(
    const float* __restrict__ prev, float* __restrict__ next,
    float* __restrict__ out_acc, const int* __restrict__ rp,
    const int* __restrict__ ccol, const float* __restrict__ cval,
    unsigned long long maskbits, int apply_mask, int n) {
    int wave = (int)((blockIdx.x * (unsigned)blockDim.x + threadIdx.x) >> 6);
    int lane = threadIdx.x & 63;
    if (wave >= n) return;
    int start = rp[wave], end = rp[wave + 1];
    float acc = 0.f;
    for (int e = start; e < end; e++) {
        int c = ccol[e];
        float v = cval[e];
        acc += v * prev[(size_t)c * 64 + lane];
    }
    float res;
    if (apply_mask) {
        float pv = prev[(size_t)wave * 64 + lane];
        res = ((maskbits >> lane) & 1ull) ? acc : pv;
    } else {
        res = acc;
    }
    next[(size_t)wave * 64 + lane] = res;
    out_acc[(size_t)wave * 64 + lane] += res;
}

// ---------------------------------------------------------------------------
// Final: out[b] = (1/R^2) * dot(out_acc[users[b]], out_acc[U+items[b]])
// ---------------------------------------------------------------------------
__global__ __launch_bounds__(256) void dot_kernel(
    const float* __restrict__ out_acc, const int* __restrict__ users,
    const int* __restrict__ items, float* __restrict__ out,
    int Bn, int U, float scale) {
    int w = (int)((blockIdx.x * (unsigned)blockDim.x + threadIdx.x) >> 6);
    int lane = threadIdx.x & 63;
    if (w >= Bn) return;
    int u = users[w], it = items[w];
    float a = out_acc[(size_t)u * 64 + lane];
    float c = out_acc[((size_t)(U + it)) * 64 + lane];
    float p = a * c;
    #pragma unroll
    for (int off = 32; off > 0; off >>= 1) p += __shfl_down(p, off);
    if (lane == 0) out[w] = p * scale;
}

// ---------------------------------------------------------------------------
extern "C" void kernel_launch(void* const* d_in, const int* in_sizes, int n_in,
                              void* d_out, int out_size, void* d_ws, size_t ws_size,
                              hipStream_t stream) {
    const int* users = (const int*)d_in[0];
    const int* items = (const int*)d_in[1];
    const float* user_emb = (const float*)d_in[2];
    const float* item_emb = (const float*)d_in[3];
    const float* rating_emb = (const float*)d_in[4];
    const float* W1 = (const float*)d_in[5];
    const float* b1 = (const float*)d_in[6];
    const float* W2 = (const float*)d_in[7];
    const float* b2 = (const float*)d_in[8];
    const int* rows = (const int*)d_in[9];
    const int* cols = (const int*)d_in[10];
    const float* vals = (const float*)d_in[11];
    float* out = (float*)d_out;

    const int Dd = 64;
    int U = in_sizes[2] / Dd;
    int I = in_sizes[3] / Dd;
    int R = in_sizes[4] / Dd;
    int N = U + I;
    int E = in_sizes[9] / R;
    int Bn = in_sizes[0];

    char* p = (char*)d_ws;
    auto carve = [&](size_t bytes) -> char* {
        char* q = p;
        p += (bytes + 255) & ~(size_t)255;
        return q;
    };
    float* out_acc = (float*)carve((size_t)N * 64 * 4);
    float* bufA = (float*)carve((size_t)N * 64 * 4);
    float* bufB = (float*)carve((size_t)N * 64 * 4);
    int* row_ptr = (int*)carve((size_t)(N + 1) * 4);
    int* cnt = (int*)carve((size_t)N * 4);
    int* bsums = (int*)carve(4096);
    int* ccol = (int*)carve((size_t)E * 4);
    float* cval = (float*)carve((size_t)E * 4);

    uint64_t maskbits = compute_mask_bits();

    hipMemsetAsync(out_acc, 0, (size_t)N * 64 * 4, stream);

    int NB1 = (N + 1023) / 1024;
    int spmm_blocks = (N + 3) / 4;
    for (int r = 0; r < R; r++) {
        const int* rows_r = rows + (size_t)r * E;
        const int* cols_r = cols + (size_t)r * E;
        const float* vals_r = vals + (size_t)r * E;

        hipMemsetAsync(cnt, 0, (size_t)N * 4, stream);
        hist_kernel<<<(E + 255) / 256, 256, 0, stream>>>(rows_r, cnt, E);
        scan1_kernel<<<NB1, 256, 0, stream>>>(cnt, row_ptr, bsums, N);
        scan2_kernel<<<1, 256, 0, stream>>>(bsums, NB1);
        scan3_kernel<<<(N + 255) / 256, 256, 0, stream>>>(row_ptr, bsums, N, E);
        hipMemsetAsync(cnt, 0, (size_t)N * 4, stream);
        scatter_kernel<<<(E + 255) / 256, 256, 0, stream>>>(rows_r, cols_r, vals_r,
                                                            row_ptr, cnt, ccol, cval, E);

        mlp_kernel<<<(N + 63) / 64, 256, 0, stream>>>(user_emb, item_emb, rating_emb,
                                                      W1, b1, W2, b2, bufA, out_acc,
                                                      r, N, U);

        spmm_kernel<<<spmm_blocks, 256, 0, stream>>>(bufA, bufB, out_acc, row_ptr,
                                                     ccol, cval, maskbits, 0, N);
        spmm_kernel<<<spmm_blocks, 256, 0, stream>>>(bufB, bufA, out_acc, row_ptr,
                                                     ccol, cval, maskbits, 0, N);
        spmm_kernel<<<spmm_blocks, 256, 0, stream>>>(bufA, bufB, out_acc, row_ptr,
                                                     ccol, cval, maskbits, 1, N);
    }

    float scale = 1.0f / (float)(R * R);
    dot_kernel<<<(Bn * 64 + 255) / 256, 256, 0, stream>>>(out_acc, users, items, out,
                                                          Bn, U, scale);
}

// Round 2
// 1643.006 us; speedup vs baseline: 1.5660x; 1.5660x over previous
//
#include <hip/hip_runtime.h>
#include <hip/hip_bf16.h>
#include <cstdint>
#include <cstddef>

// ---------------------------------------------------------------------------
// Host-side reproduction of np.random.RandomState(2).permutation(64):
// MT19937 seeded with init_genrand(2), Fisher-Yates with numpy's
// random_interval (mask+rejection). Mask bit d = (perm[d] >= 38).
// ---------------------------------------------------------------------------
static uint64_t compute_mask_bits() {
    uint32_t mt[624];
    mt[0] = 2u;
    for (int i = 1; i < 624; i++)
        mt[i] = 1812433253u * (mt[i - 1] ^ (mt[i - 1] >> 30)) + (uint32_t)i;
    int mti = 624;
    auto genrand = [&]() -> uint32_t {
        if (mti >= 624) {
            for (int k = 0; k < 624; k++) {
                uint32_t y = (mt[k] & 0x80000000u) | (mt[(k + 1) % 624] & 0x7fffffffu);
                mt[k] = mt[(k + 397) % 624] ^ (y >> 1) ^ ((y & 1u) ? 2567483615u : 0u);
            }
            mti = 0;
        }
        uint32_t y = mt[mti++];
        y ^= y >> 11;
        y ^= (y << 7) & 2636928640u;
        y ^= (y << 15) & 4022730752u;
        y ^= y >> 18;
        return y;
    };
    int arr[64];
    for (int i = 0; i < 64; i++) arr[i] = i;
    for (int i = 63; i >= 1; i--) {
        uint32_t mask = (uint32_t)i;
        mask |= mask >> 1; mask |= mask >> 2; mask |= mask >> 4;
        mask |= mask >> 8; mask |= mask >> 16;
        uint32_t v;
        do { v = genrand() & mask; } while (v > (uint32_t)i);
        int tmp = arr[i]; arr[i] = arr[v]; arr[v] = tmp;
    }
    uint64_t bits = 0;
    for (int d = 0; d < 64; d++)
        if (arr[d] >= 38) bits |= (1ull << d);
    return bits;
}

// ---------------------------------------------------------------------------
// Output-row flag set: rows actually read by the final dot.
// ---------------------------------------------------------------------------
__global__ void flag_kernel(const int* __restrict__ users, const int* __restrict__ items,
                            unsigned char* __restrict__ flag, int B, int U) {
    int i = blockIdx.x * 256 + threadIdx.x;
    if (i < B) flag[users[i]] = 1;
    else if (i < 2 * B) flag[U + items[i - B]] = 1;
}

__global__ void flist_kernel(const unsigned char* __restrict__ flag,
                             int* __restrict__ flist, int* __restrict__ fcount, int n) {
    int i = blockIdx.x * 256 + threadIdx.x;
    if (i < n && flag[i]) {
        int p = atomicAdd(fcount, 1);
        flist[p] = i;
    }
}

// ---------------------------------------------------------------------------
// CSR build kernels
// ---------------------------------------------------------------------------
__global__ void hist_kernel(const int* __restrict__ rows, int* __restrict__ cnt, int e) {
    int i = blockIdx.x * 256 + threadIdx.x;
    if (i < e) atomicAdd(&cnt[rows[i]], 1);
}

__global__ void scan1_kernel(const int* __restrict__ cnt, int* __restrict__ rp,
                             int* __restrict__ bsums, int n) {
    __shared__ int sh[256];
    int t = threadIdx.x;
    int base = blockIdx.x * 1024 + t * 4;
    int v0 = 0, v1 = 0, v2 = 0, v3 = 0;
    if (base + 3 < n) {
        int4 q = *(const int4*)(cnt + base);
        v0 = q.x; v1 = q.y; v2 = q.z; v3 = q.w;
    } else {
        if (base + 0 < n) v0 = cnt[base + 0];
        if (base + 1 < n) v1 = cnt[base + 1];
        if (base + 2 < n) v2 = cnt[base + 2];
        if (base + 3 < n) v3 = cnt[base + 3];
    }
    int total = v0 + v1 + v2 + v3;
    sh[t] = total;
    __syncthreads();
    for (int off = 1; off < 256; off <<= 1) {
        int x = (t >= off) ? sh[t - off] : 0;
        __syncthreads();
        sh[t] += x;
        __syncthreads();
    }
    int excl = sh[t] - total;
    if (base + 0 < n) rp[base + 0] = excl;
    if (base + 1 < n) rp[base + 1] = excl + v0;
    if (base + 2 < n) rp[base + 2] = excl + v0 + v1;
    if (base + 3 < n) rp[base + 3] = excl + v0 + v1 + v2;
    if (t == 255) bsums[blockIdx.x] = sh[255];
}

__global__ void scan2_kernel(int* __restrict__ bsums, int nb) {
    __shared__ int sh[256];
    int t = threadIdx.x;
    int base = t * 4;
    int v[4]; int s = 0;
    #pragma unroll
    for (int j = 0; j < 4; j++) {
        v[j] = (base + j < nb) ? bsums[base + j] : 0;
        s += v[j];
    }
    sh[t] = s;
    __syncthreads();
    for (int off = 1; off < 256; off <<= 1) {
        int x = (t >= off) ? sh[t - off] : 0;
        __syncthreads();
        sh[t] += x;
        __syncthreads();
    }
    int run = sh[t] - s;
    #pragma unroll
    for (int j = 0; j < 4; j++) {
        if (base + j < nb) bsums[base + j] = run;
        run += v[j];
    }
}

__global__ void scan3_kernel(int* __restrict__ rp, const int* __restrict__ bsums,
                             int n, int e_total) {
    int i = blockIdx.x * 256 + threadIdx.x;
    if (i < n) rp[i] += bsums[i >> 10];
    if (i == 0) rp[n] = e_total;
}

__global__ void scatter_kernel(const int* __restrict__ rows, const int* __restrict__ cols,
                               const float* __restrict__ vals, const int* __restrict__ rp,
                               int* __restrict__ cur, int* __restrict__ ccol,
                               float* __restrict__ cval, int e) {
    int i = blockIdx.x * 256 + threadIdx.x;
    if (i >= e) return;
    int rsrc = rows[i];
    int pos = rp[rsrc] + atomicAdd(&cur[rsrc], 1);
    ccol[pos] = cols[i];
    cval[pos] = vals[i];
}

// ---------------------------------------------------------------------------
// Per-rating MLP: h = leaky_relu(x @ W1a + c1) @ W2 + b2
// prev = h for all rows; out_acc += h only for flagged rows.
// ---------------------------------------------------------------------------
__global__ __launch_bounds__(256) void mlp_kernel(
    const float* __restrict__ user_emb, const float* __restrict__ item_emb,
    const float* __restrict__ rating_emb, const float* __restrict__ W1,
    const float* __restrict__ b1, const float* __restrict__ W2,
    const float* __restrict__ b2, float* __restrict__ prev,
    float* __restrict__ out_acc, const unsigned char* __restrict__ flag,
    int r, int n_rows, int U) {
    __shared__ float sW1[64 * 64];  // [k][j]
    __shared__ float sW2[64 * 64];  // [k][j]
    __shared__ float sXT[64 * 64];  // [k][i]
    __shared__ float sTT[64 * 64];  // [k][i]
    __shared__ float sc1[64];
    __shared__ float sb2v[64];

    int t = threadIdx.x;
    int row0 = blockIdx.x * 64;
    const float* W1r = W1 + (size_t)r * (128 * 64);
    const float* W2r = W2 + (size_t)r * (64 * 64);

    #pragma unroll
    for (int q = 0; q < 4; q++) {
        int f = t + 256 * q;
        int k = f >> 4, c = (f & 15) * 4;
        *(float4*)(sW1 + k * 64 + c) = *(const float4*)(W1r + k * 64 + c);
        *(float4*)(sW2 + k * 64 + c) = *(const float4*)(W2r + k * 64 + c);
    }
    #pragma unroll
    for (int q = 0; q < 4; q++) {
        int f = t + 256 * q;
        int i = f >> 4, c = (f & 15) * 4;
        int nrow = row0 + i;
        float4 xv = make_float4(0.f, 0.f, 0.f, 0.f);
        if (nrow < n_rows) {
            const float* src = (nrow < U) ? (user_emb + (size_t)nrow * 64)
                                          : (item_emb + (size_t)(nrow - U) * 64);
            xv = *(const float4*)(src + c);
        }
        sXT[(c + 0) * 64 + i] = xv.x;
        sXT[(c + 1) * 64 + i] = xv.y;
        sXT[(c + 2) * 64 + i] = xv.z;
        sXT[(c + 3) * 64 + i] = xv.w;
    }
    if (t < 64) {
        float acc = b1[r * 64 + t];
        for (int k = 0; k < 64; k++)
            acc += rating_emb[r * 64 + k] * W1r[(64 + k) * 64 + t];
        sc1[t] = acc;
    } else if (t < 128) {
        sb2v[t - 64] = b2[r * 64 + (t - 64)];
    }
    __syncthreads();

    int i0 = (t & 15) * 4, j0 = (t >> 4) * 4;
    float acc[4][4];
    #pragma unroll
    for (int a = 0; a < 4; a++)
        #pragma unroll
        for (int b = 0; b < 4; b++) acc[a][b] = sc1[j0 + b];
    for (int k = 0; k < 64; k++) {
        float4 xv = *(const float4*)(sXT + k * 64 + i0);
        float4 wv = *(const float4*)(sW1 + k * 64 + j0);
        float xs[4] = {xv.x, xv.y, xv.z, xv.w};
        float ws[4] = {wv.x, wv.y, wv.z, wv.w};
        #pragma unroll
        for (int a = 0; a < 4; a++)
            #pragma unroll
            for (int b = 0; b < 4; b++) acc[a][b] += xs[a] * ws[b];
    }
    #pragma unroll
    for (int a = 0; a < 4; a++)
        #pragma unroll
        for (int b = 0; b < 4; b++) {
            float v = acc[a][b];
            v = (v >= 0.f) ? v : 0.01f * v;
            sTT[(j0 + b) * 64 + (i0 + a)] = v;
        }
    __syncthreads();

    #pragma unroll
    for (int a = 0; a < 4; a++)
        #pragma unroll
        for (int b = 0; b < 4; b++) acc[a][b] = sb2v[j0 + b];
    for (int k = 0; k < 64; k++) {
        float4 xv = *(const float4*)(sTT + k * 64 + i0);
        float4 wv = *(const float4*)(sW2 + k * 64 + j0);
        float xs[4] = {xv.x, xv.y, xv.z, xv.w};
        float ws[4] = {wv.x, wv.y, wv.z, wv.w};
        #pragma unroll
        for (int a = 0; a < 4; a++)
            #pragma unroll
            for (int b = 0; b < 4; b++) acc[a][b] += xs[a] * ws[b];
    }
    #pragma unroll
    for (int a = 0; a < 4; a++) {
        int nrow = row0 + i0 + a;
        if (nrow < n_rows) {
            float4 hv = make_float4(acc[a][0], acc[a][1], acc[a][2], acc[a][3]);
            *(float4*)(prev + (size_t)nrow * 64 + j0) = hv;
            if (flag[nrow]) {
                float4 ov = *(const float4*)(out_acc + (size_t)nrow * 64 + j0);
                ov.x += hv.x; ov.y += hv.y; ov.z += hv.z; ov.w += hv.w;
                *(float4*)(out_acc + (size_t)nrow * 64 + j0) = ov;
            }
        }
    }
}

// ---------------------------------------------------------------------------
// Gather-SpMM (layers 0/1, mask = all-ones): one wave per row, 4x unrolled
// edge loop for memory-level parallelism. out_acc += only for flagged rows.
// ---------------------------------------------------------------------------
__global__ __launch_bounds__(256) void spmm_kernel(
    const float* __restrict__ prev, float* __restrict__ next,
    float* __restrict__ out_acc, const int* __restrict__ rp,
    const int* __restrict__ ccol, const float* __restrict__ cval,
    const unsigned char* __restrict__ flag, int n) {
    int wave = (int)((blockIdx.x * (unsigned)blockDim.x + threadIdx.x) >> 6);
    int lane = threadIdx.x & 63;
    if (wave >= n) return;
    int start = rp[wave], end = rp[wave + 1];
    float acc = 0.f;
    int e = start;
    for (; e + 3 < end; e += 4) {
        int c0 = ccol[e + 0], c1 = ccol[e + 1], c2 = ccol[e + 2], c3 = ccol[e + 3];
        float v0 = cval[e + 0], v1 = cval[e + 1], v2 = cval[e + 2], v3 = cval[e + 3];
        float p0 = prev[(size_t)c0 * 64 + lane];
        float p1 = prev[(size_t)c1 * 64 + lane];
        float p2 = prev[(size_t)c2 * 64 + lane];
        float p3 = prev[(size_t)c3 * 64 + lane];
        acc += v0 * p0; acc += v1 * p1; acc += v2 * p2; acc += v3 * p3;
    }
    for (; e < end; e++) {
        acc += cval[e] * prev[(size_t)ccol[e] * 64 + lane];
    }
    next[(size_t)wave * 64 + lane] = acc;
    if (flag[wave]) out_acc[(size_t)wave * 64 + lane] += acc;
}

// ---------------------------------------------------------------------------
// Layer-2 (masked) SpMM: only for rows in flist (rows the final dot reads).
// No `next` write — this is the last propagation layer.
// ---------------------------------------------------------------------------
__global__ __launch_bounds__(256) void spmm_masked_kernel(
    const float* __restrict__ prev, float* __restrict__ out_acc,
    const int* __restrict__ rp, const int* __restrict__ ccol,
    const float* __restrict__ cval, unsigned long long maskbits,
    const int* __restrict__ flist, const int* __restrict__ fcount) {
    int w = (int)((blockIdx.x * (unsigned)blockDim.x + threadIdx.x) >> 6);
    int lane = threadIdx.x & 63;
    if (w >= *fcount) return;
    int row = flist[w];
    int start = rp[row], end = rp[row + 1];
    float acc = 0.f;
    int e = start;
    for (; e + 3 < end; e += 4) {
        int c0 = ccol[e + 0], c1 = ccol[e + 1], c2 = ccol[e + 2], c3 = ccol[e + 3];
        float v0 = cval[e + 0], v1 = cval[e + 1], v2 = cval[e + 2], v3 = cval[e + 3];
        float p0 = prev[(size_t)c0 * 64 + lane];
        float p1 = prev[(size_t)c1 * 64 + lane];
        float p2 = prev[(size_t)c2 * 64 + lane];
        float p3 = prev[(size_t)c3 * 64 + lane];
        acc += v0 * p0; acc += v1 * p1; acc += v2 * p2; acc += v3 * p3;
    }
    for (; e < end; e++) {
        acc += cval[e] * prev[(size_t)ccol[e] * 64 + lane];
    }
    float pv = prev[(size_t)row * 64 + lane];
    float res = ((maskbits >> lane) & 1ull) ? acc : pv;
    out_acc[(size_t)row * 64 + lane] += res;
}

// ---------------------------------------------------------------------------
// Final: out[b] = (1/R^2) * dot(out_acc[users[b]], out_acc[U+items[b]])
// ---------------------------------------------------------------------------
__global__ __launch_bounds__(256) void dot_kernel(
    const float* __restrict__ out_acc, const int* __restrict__ users,
    const int* __restrict__ items, float* __restrict__ out,
    int Bn, int U, float scale) {
    int w = (int)((blockIdx.x * (unsigned)blockDim.x + threadIdx.x) >> 6);
    int lane = threadIdx.x & 63;
    if (w >= Bn) return;
    int u = users[w], it = items[w];
    float a = out_acc[(size_t)u * 64 + lane];
    float c = out_acc[((size_t)(U + it)) * 64 + lane];
    float p = a * c;
    #pragma unroll
    for (int off = 32; off > 0; off >>= 1) p += __shfl_down(p, off);
    if (lane == 0) out[w] = p * scale;
}

// ---------------------------------------------------------------------------
extern "C" void kernel_launch(void* const* d_in, const int* in_sizes, int n_in,
                              void* d_out, int out_size, void* d_ws, size_t ws_size,
                              hipStream_t stream) {
    const int* users = (const int*)d_in[0];
    const int* items = (const int*)d_in[1];
    const float* user_emb = (const float*)d_in[2];
    const float* item_emb = (const float*)d_in[3];
    const float* rating_emb = (const float*)d_in[4];
    const float* W1 = (const float*)d_in[5];
    const float* b1 = (const float*)d_in[6];
    const float* W2 = (const float*)d_in[7];
    const float* b2 = (const float*)d_in[8];
    const int* rows = (const int*)d_in[9];
    const int* cols = (const int*)d_in[10];
    const float* vals = (const float*)d_in[11];
    float* out = (float*)d_out;

    const int Dd = 64;
    int U = in_sizes[2] / Dd;
    int I = in_sizes[3] / Dd;
    int R = in_sizes[4] / Dd;
    int N = U + I;
    int E = in_sizes[9] / R;
    int Bn = in_sizes[0];

    char* p = (char*)d_ws;
    auto carve = [&](size_t bytes) -> char* {
        char* q = p;
        p += (bytes + 255) & ~(size_t)255;
        return q;
    };
    float* out_acc = (float*)carve((size_t)N * 64 * 4);
    float* bufA = (float*)carve((size_t)N * 64 * 4);
    float* bufB = (float*)carve((size_t)N * 64 * 4);
    int* row_ptr = (int*)carve((size_t)(N + 1) * 4);
    int* cnt = (int*)carve((size_t)N * 4);
    int* bsums = (int*)carve(4096);
    int* ccol = (int*)carve((size_t)E * 4);
    float* cval = (float*)carve((size_t)E * 4);
    unsigned char* flag = (unsigned char*)carve((size_t)N);
    int* flist = (int*)carve((size_t)2 * Bn * 4);
    int* fcount = (int*)carve(4);

    uint64_t maskbits = compute_mask_bits();

    hipMemsetAsync(out_acc, 0, (size_t)N * 64 * 4, stream);
    hipMemsetAsync(flag, 0, (size_t)N, stream);
    hipMemsetAsync(fcount, 0, 4, stream);

    flag_kernel<<<(2 * Bn + 255) / 256, 256, 0, stream>>>(users, items, flag, Bn, U);
    flist_kernel<<<(N + 255) / 256, 256, 0, stream>>>(flag, flist, fcount, N);

    int NB1 = (N + 1023) / 1024;
    int spmm_blocks = (N + 3) / 4;
    int masked_blocks = (2 * Bn + 3) / 4;  // upper bound on |flist| waves
    for (int r = 0; r < R; r++) {
        const int* rows_r = rows + (size_t)r * E;
        const int* cols_r = cols + (size_t)r * E;
        const float* vals_r = vals + (size_t)r * E;

        hipMemsetAsync(cnt, 0, (size_t)N * 4, stream);
        hist_kernel<<<(E + 255) / 256, 256, 0, stream>>>(rows_r, cnt, E);
        scan1_kernel<<<NB1, 256, 0, stream>>>(cnt, row_ptr, bsums, N);
        scan2_kernel<<<1, 256, 0, stream>>>(bsums, NB1);
        scan3_kernel<<<(N + 255) / 256, 256, 0, stream>>>(row_ptr, bsums, N, E);
        hipMemsetAsync(cnt, 0, (size_t)N * 4, stream);
        scatter_kernel<<<(E + 255) / 256, 256, 0, stream>>>(rows_r, cols_r, vals_r,
                                                            row_ptr, cnt, ccol, cval, E);

        mlp_kernel<<<(N + 63) / 64, 256, 0, stream>>>(user_emb, item_emb, rating_emb,
                                                      W1, b1, W2, b2, bufA, out_acc,
                                                      flag, r, N, U);

        spmm_kernel<<<spmm_blocks, 256, 0, stream>>>(bufA, bufB, out_acc, row_ptr,
                                                     ccol, cval, flag, N);
        spmm_kernel<<<spmm_blocks, 256, 0, stream>>>(bufB, bufA, out_acc, row_ptr,
                                                     ccol, cval, flag, N);
        spmm_masked_kernel<<<masked_blocks, 256, 0, stream>>>(bufA, out_acc, row_ptr,
                                                              ccol, cval, maskbits,
                                                              flist, fcount);
    }

    float scale = 1.0f / (float)(R * R);
    dot_kernel<<<(Bn * 64 + 255) / 256, 256, 0, stream>>>(out_acc, users, items, out,
                                                          Bn, U, scale);
}